// Round 7
// baseline (173.776 us; speedup 1.0000x reference)
//
#include <hip/hip_runtime.h>
#include <hip/hip_bf16.h>

// Problem constants (B,G,D,H,K,V) = (4, 2048, 128, 8, 16, 16)
#define GG 2048
#define DD 128
#define HH 8
#define BH 32

typedef _Float16 h2 __attribute__((ext_vector_type(2)));
typedef _Float16 h4 __attribute__((ext_vector_type(4)));
typedef _Float16 h8 __attribute__((ext_vector_type(8)));
typedef __attribute__((ext_vector_type(4))) float f32x4;
typedef unsigned short u16;
typedef unsigned int   u32;
typedef unsigned char  u8;
typedef unsigned long long u64;

// 0.25 (=1/sqrt(16)) * log2(e): folded into W_Q so softmax uses raw exp2.
#define QSCALE 0.36067376022224085f

// ws layout (f16), ~8.6 MB total
#define OFF_Q 0u            // f16 [BH][G][16] (scaled)   2 MB
#define OFF_K (2u << 20)    // f16 [BH][G][16]            2 MB
#define OFF_V (4u << 20)    // f16 [BH][16][G] (V^T)      2 MB
#define OFF_M (6u << 20)    // u8  [G][G/8] mask bytes  512 KB
#define OFF_H 6815744u      // f16 h [B][G][128]          2 MB
#define OFF_W 8912896u      // f16 Wc [H][48][128]       96 KB

#if __has_builtin(__builtin_amdgcn_exp2f)
#define EXP2F(x) __builtin_amdgcn_exp2f(x)
#else
#define EXP2F(x) exp2f(x)
#endif

// Legacy K=16 f16 MFMA (no underscore before f16 — gfx908-era naming).
#define MFMA16(a, b, c) __builtin_amdgcn_mfma_f32_16x16x16f16(a, b, c, 0, 0, 0)

// ---------------------------------------------------------------------------
// Kernel 1 (fused streaming prep):
//   blocks [0,512):      h fp32 -> f16            (8 elems/thread)
//   blocks [512,704):    W pack -> Wc[h][48][128] f16, QSCALE in Q cols
//   blocks [704,2752):   mask int32 -> byte map   (8 elems/thread, 1 u8 store)
// ---------------------------------------------------------------------------
__global__ __launch_bounds__(256) void prep_kernel(
    const float* __restrict__ h, const int* __restrict__ mask,
    const float* __restrict__ WQ, const float* __restrict__ WK,
    const float* __restrict__ WV,
    _Float16* __restrict__ hF, _Float16* __restrict__ Wc, u8* __restrict__ mb)
{
  const int blk = blockIdx.x, tid = threadIdx.x;
  if (blk < 512) {                       // ---- h convert ----
    int i = (blk * 256 + tid) * 8;
    float4 a = *(const float4*)(h + i);
    float4 b = *(const float4*)(h + i + 4);
    h8 o = { (_Float16)a.x, (_Float16)a.y, (_Float16)a.z, (_Float16)a.w,
             (_Float16)b.x, (_Float16)b.y, (_Float16)b.z, (_Float16)b.w };
    *(h8*)(hF + i) = o;
  } else if (blk < 704) {                // ---- W pack ----
    int j = (blk - 512) * 256 + tid;     // [0, 49152)
    int hh = j / (48 * DD);
    int r  = j % (48 * DD);
    int n  = r / DD;
    int d  = r % DD;
    float val;
    if (n < 16)      val = WQ[((size_t)hh * DD + d) * 16 + n] * QSCALE;
    else if (n < 32) val = WK[((size_t)hh * DD + d) * 16 + (n - 16)];
    else             val = WV[((size_t)hh * DD + d) * 16 + (n - 32)];
    Wc[j] = (_Float16)val;
  } else {                               // ---- mask byte map ----
    int t = (blk - 704) * 256 + tid;     // [0, 524288)
    const int* m = mask + (size_t)t * 8;
    int4 m0 = *(const int4*)m;
    int4 m1 = *(const int4*)(m + 4);
    u32 byte = (m0.x > 0) | ((m0.y > 0) << 1) | ((m0.z > 0) << 2) | ((m0.w > 0) << 3)
             | ((m1.x > 0) << 4) | ((m1.y > 0) << 5) | ((m1.z > 0) << 6) | ((m1.w > 0) << 7);
    mb[t] = (u8)byte;
  }
}

// ---------------------------------------------------------------------------
// Kernel 2: MFMA projection (f16). One wave per (bh, 64-row g-tile):
// [64x128] x [128x48] via 4 m-tiles x 3 n-tiles x 4 k-steps of 16x16x32_f16.
// ---------------------------------------------------------------------------
__global__ __launch_bounds__(64) void proj_mfma(
    const _Float16* __restrict__ hF, const _Float16* __restrict__ Wc,
    _Float16* __restrict__ Qh, _Float16* __restrict__ Kh, _Float16* __restrict__ Vt)
{
  const int bh = blockIdx.x >> 5;
  const int gt = blockIdx.x & 31;
  const int b  = bh >> 3;
  const int hh = bh & (HH - 1);
  const int lane = threadIdx.x;
  const int col  = lane & 15;
  const int quad = lane >> 4;
  const int g0 = gt * 64;

  const _Float16* hb = hF + (size_t)b * GG * DD;
  const _Float16* W  = Wc + (size_t)hh * 48 * DD;

  f32x4 acc[4][3];
  #pragma unroll
  for (int mt = 0; mt < 4; ++mt)
    #pragma unroll
    for (int nt = 0; nt < 3; ++nt)
      acc[mt][nt] = (f32x4){0.f, 0.f, 0.f, 0.f};

  #pragma unroll
  for (int s = 0; s < 4; ++s) {
    h8 a[4], bw[3];
    #pragma unroll
    for (int mt = 0; mt < 4; ++mt)
      a[mt] = *(const h8*)(hb + (size_t)(g0 + mt * 16 + col) * DD + s * 32 + quad * 8);
    #pragma unroll
    for (int nt = 0; nt < 3; ++nt)
      bw[nt] = *(const h8*)(W + (size_t)(nt * 16 + col) * DD + s * 32 + quad * 8);
    #pragma unroll
    for (int mt = 0; mt < 4; ++mt)
      #pragma unroll
      for (int nt = 0; nt < 3; ++nt)
        acc[mt][nt] = __builtin_amdgcn_mfma_f32_16x16x32_f16(a[mt], bw[nt], acc[mt][nt], 0, 0, 0);
  }

  #pragma unroll
  for (int mt = 0; mt < 4; ++mt) {
    #pragma unroll
    for (int r = 0; r < 4; ++r) {
      int g = g0 + mt * 16 + quad * 4 + r;
      Qh[((size_t)bh * GG + g) * 16 + col] = (_Float16)acc[mt][0][r];
      Kh[((size_t)bh * GG + g) * 16 + col] = (_Float16)acc[mt][1][r];
      Vt[((size_t)bh * 16 + col) * GG + g] = (_Float16)acc[mt][2][r];
    }
  }
}

// ---------------------------------------------------------------------------
// Kernel 3: flash attention, zero LDS, latency-pipelined.
// 16 q-rows/wave; keys split into 2 independent streams (0..1023, 1024..2047)
// with separate acc/lsum -> 2x independent chains, half-length acc chain.
// Groups of 4 tiles/stream (64 keys); all 16 fragments + 2 mask words of
// group g+1 are loaded into explicit double-buffer registers at the top of
// group g -> ~16 loads in flight during every compute body (the r6 kernel's
// VGPR=28 showed the compiler was issuing loads just-in-time, ~400 cyc/iter).
// ---------------------------------------------------------------------------
__global__ __launch_bounds__(256) void attn_kernel(
    const _Float16* __restrict__ Qh, const _Float16* __restrict__ Kh,
    const _Float16* __restrict__ Vt, const u8* __restrict__ mb,
    float* __restrict__ out)
{
  const int tid = threadIdx.x, wave = tid >> 6, lane = tid & 63;
  const int col = lane & 15, quad = lane >> 4;
  const int bh = blockIdx.x >> 5;
  const int qb = (blockIdx.x & 31) * 64 + wave * 16;

  // Q B-frag (16x16x16): B[k=dim][n=q]: n=col, k=quad*4+j  -> 8B load
  const h4 qf = *(const h4*)(Qh + ((size_t)bh * GG + qb + col) * 16 + quad * 4);

  const _Float16* Kb = Kh + (size_t)bh * GG * 16;
  const _Float16* Vb = Vt + ((size_t)bh * 16 + col) * GG;   // row col = vdim
  const u64* mrow = (const u64*)(mb + (size_t)(qb + col) * (GG / 8)); // 32 words

  f32x4 accA = {0.f,0.f,0.f,0.f}, accB = {0.f,0.f,0.f,0.f};
  const f32x4 cinit = {-4.f, -4.f, -4.f, -4.f};
  float lsA = 0.f, lsB = 0.f;
  const int shq = quad * 4;

  // ---- prologue: load group 0 of both streams ----
  h4 kA[4], vA[4], kB[4], vB[4];
  u64 wA, wB;
  #pragma unroll
  for (int t = 0; t < 4; ++t) {
    kA[t] = *(const h4*)(Kb + (size_t)(t * 16 + col) * 16 + shq);
    vA[t] = *(const h4*)(Vb + t * 16 + shq);
    kB[t] = *(const h4*)(Kb + (size_t)(1024 + t * 16 + col) * 16 + shq);
    vB[t] = *(const h4*)(Vb + 1024 + t * 16 + shq);
  }
  wA = mrow[0];
  wB = mrow[16];

  for (int g = 0; g < 16; ++g) {
    // ---- prefetch group g+1 (wraps to 0 on last iter — harmless reload) ----
    const int gn = (g + 1) & 15;
    const int kbA = gn * 64, kbB = 1024 + gn * 64;
    h4 nkA[4], nvA[4], nkB[4], nvB[4];
    #pragma unroll
    for (int t = 0; t < 4; ++t) {
      nkA[t] = *(const h4*)(Kb + (size_t)(kbA + t * 16 + col) * 16 + shq);
      nvA[t] = *(const h4*)(Vb + kbA + t * 16 + shq);
      nkB[t] = *(const h4*)(Kb + (size_t)(kbB + t * 16 + col) * 16 + shq);
      nvB[t] = *(const h4*)(Vb + kbB + t * 16 + shq);
    }
    u64 nwA = mrow[gn];
    u64 nwB = mrow[16 + gn];

    // ---- compute current group: 4 tiles per stream ----
    #pragma unroll
    for (int t = 0; t < 4; ++t) {
      const int sh = t * 16 + shq;
      f32x4 sA = MFMA16(kA[t], qf, cinit);
      f32x4 sB = MFMA16(kB[t], qf, cinit);
      u32 bA = (u32)(wA >> sh) & 0xFu;
      u32 bB = (u32)(wB >> sh) & 0xFu;

      float a0 = (bA & 1u) ? 0.f : EXP2F(sA[0]);
      float a1 = (bA & 2u) ? 0.f : EXP2F(sA[1]);
      float a2 = (bA & 4u) ? 0.f : EXP2F(sA[2]);
      float a3 = (bA & 8u) ? 0.f : EXP2F(sA[3]);
      float b0 = (bB & 1u) ? 0.f : EXP2F(sB[0]);
      float b1 = (bB & 2u) ? 0.f : EXP2F(sB[1]);
      float b2 = (bB & 4u) ? 0.f : EXP2F(sB[2]);
      float b3 = (bB & 8u) ? 0.f : EXP2F(sB[3]);
      lsA += (a0 + a1) + (a2 + a3);
      lsB += (b0 + b1) + (b2 + b3);

      h2 pa01 = __builtin_bit_cast(h2, __builtin_amdgcn_cvt_pkrtz(a0, a1));
      h2 pa23 = __builtin_bit_cast(h2, __builtin_amdgcn_cvt_pkrtz(a2, a3));
      h4 pfA = __builtin_shufflevector(pa01, pa23, 0, 1, 2, 3);
      h2 pb01 = __builtin_bit_cast(h2, __builtin_amdgcn_cvt_pkrtz(b0, b1));
      h2 pb23 = __builtin_bit_cast(h2, __builtin_amdgcn_cvt_pkrtz(b2, b3));
      h4 pfB = __builtin_shufflevector(pb01, pb23, 0, 1, 2, 3);

      accA = MFMA16(vA[t], pfA, accA);
      accB = MFMA16(vB[t], pfB, accB);
    }

    // ---- rotate double buffers ----
    #pragma unroll
    for (int t = 0; t < 4; ++t) {
      kA[t] = nkA[t]; vA[t] = nvA[t];
      kB[t] = nkB[t]; vB[t] = nvB[t];
    }
    wA = nwA; wB = nwB;
  }

  // combine streams; denominator for q=col reduced over the 4 quads
  f32x4 acc = accA + accB;
  float l = lsA + lsB;
  l += __shfl_xor(l, 16, 64);
  l += __shfl_xor(l, 32, 64);
  float rl = (l > 0.f) ? (1.f / l) : 0.f;     // all-masked row -> 0 (matches ref)

  // O^T C-layout: lane holds vdims quad*4+r of q=col -> one float4 store
  float4 o = { acc[0] * rl, acc[1] * rl, acc[2] * rl, acc[3] * rl };
  *(float4*)(out + ((size_t)bh * GG + qb + col) * 16 + quad * 4) = o;
}

// ---------------------------------------------------------------------------
extern "C" void kernel_launch(void* const* d_in, const int* in_sizes, int n_in,
                              void* d_out, int out_size, void* d_ws, size_t ws_size,
                              hipStream_t stream) {
  const float* h    = (const float*)d_in[0];
  const int*   mask = (const int*)d_in[1];
  const float* WQ   = (const float*)d_in[2];
  const float* WK   = (const float*)d_in[3];
  const float* WV   = (const float*)d_in[4];
  float* out = (float*)d_out;
  char* ws = (char*)d_ws;     // uses ~8.6 MB
  _Float16* Qh = (_Float16*)(ws + OFF_Q);
  _Float16* Kh = (_Float16*)(ws + OFF_K);
  _Float16* Vt = (_Float16*)(ws + OFF_V);
  u8*       mb = (u8*)(ws + OFF_M);
  _Float16* hF = (_Float16*)(ws + OFF_H);
  _Float16* Wc = (_Float16*)(ws + OFF_W);

  hipLaunchKernelGGL(prep_kernel, dim3(2752), dim3(256), 0, stream,
                     h, mask, WQ, WK, WV, hF, Wc, mb);
  hipLaunchKernelGGL(proj_mfma, dim3(BH * (GG / 64)), dim3(64), 0, stream,
                     hF, Wc, Qh, Kh, Vt);
  hipLaunchKernelGGL(attn_kernel, dim3(BH * (GG / 64)), dim3(256), 0, stream,
                     Qh, Kh, Vt, mb, out);
}

// Round 8
// 123.576 us; speedup vs baseline: 1.4062x; 1.4062x over previous
//
#include <hip/hip_runtime.h>
#include <hip/hip_bf16.h>

// Problem constants (B,G,D,H,K,V) = (4, 2048, 128, 8, 16, 16)
#define GG 2048
#define DD 128
#define HH 8
#define BH 32

typedef _Float16 h2 __attribute__((ext_vector_type(2)));
typedef _Float16 h4 __attribute__((ext_vector_type(4)));
typedef _Float16 h8 __attribute__((ext_vector_type(8)));
typedef __attribute__((ext_vector_type(4))) float f32x4;
typedef unsigned short u16;
typedef unsigned int   u32;
typedef unsigned char  u8;
typedef unsigned long long u64;

// 0.25 (=1/sqrt(16)) * log2(e): folded into W_Q so softmax uses raw exp2.
#define QSCALE 0.36067376022224085f

// ws layout (f16), ~8.6 MB total
#define OFF_Q 0u            // f16 [BH][G][16] (scaled)   2 MB
#define OFF_K (2u << 20)    // f16 [BH][G][16]            2 MB
#define OFF_V (4u << 20)    // f16 [BH][16][G] (V^T)      2 MB
#define OFF_M (6u << 20)    // u8  mbt[16][G][16] transposed mask bits  512 KB
#define OFF_H 6815744u      // f16 h [B][G][128]          2 MB
#define OFF_W 8912896u      // f16 Wc [H][48][128]       96 KB

#if __has_builtin(__builtin_amdgcn_exp2f)
#define EXP2F(x) __builtin_amdgcn_exp2f(x)
#else
#define EXP2F(x) exp2f(x)
#endif

// Legacy K=16 f16 MFMA (no underscore before f16 — gfx908-era naming).
#define MFMA16(a, b, c) __builtin_amdgcn_mfma_f32_16x16x16f16(a, b, c, 0, 0, 0)

// ---------------------------------------------------------------------------
// Kernel 1 (fused streaming prep):
//   blocks [0,512):      h fp32 -> f16            (8 elems/thread)
//   blocks [512,704):    W pack -> Wc[h][48][128] f16, QSCALE in Q cols
//   blocks [704,2752):   mask int32 -> TRANSPOSED byte map mbt[g8][q][16]
//                        (so attn's mask loads are 256B-contiguous per wave)
// ---------------------------------------------------------------------------
__global__ __launch_bounds__(256) void prep_kernel(
    const float* __restrict__ h, const int* __restrict__ mask,
    const float* __restrict__ WQ, const float* __restrict__ WK,
    const float* __restrict__ WV,
    _Float16* __restrict__ hF, _Float16* __restrict__ Wc, u8* __restrict__ mbt)
{
  const int blk = blockIdx.x, tid = threadIdx.x;
  if (blk < 512) {                       // ---- h convert ----
    int i = (blk * 256 + tid) * 8;
    float4 a = *(const float4*)(h + i);
    float4 b = *(const float4*)(h + i + 4);
    h8 o = { (_Float16)a.x, (_Float16)a.y, (_Float16)a.z, (_Float16)a.w,
             (_Float16)b.x, (_Float16)b.y, (_Float16)b.z, (_Float16)b.w };
    *(h8*)(hF + i) = o;
  } else if (blk < 704) {                // ---- W pack ----
    int j = (blk - 512) * 256 + tid;     // [0, 49152)
    int hh = j / (48 * DD);
    int r  = j % (48 * DD);
    int n  = r / DD;
    int d  = r % DD;
    float val;
    if (n < 16)      val = WQ[((size_t)hh * DD + d) * 16 + n] * QSCALE;
    else if (n < 32) val = WK[((size_t)hh * DD + d) * 16 + (n - 16)];
    else             val = WV[((size_t)hh * DD + d) * 16 + (n - 32)];
    Wc[j] = (_Float16)val;
  } else {                               // ---- mask -> transposed byte map ----
    int t = (blk - 704) * 256 + tid;     // [0, 524288)
    const int* m = mask + (size_t)t * 8;
    int4 m0 = *(const int4*)m;
    int4 m1 = *(const int4*)(m + 4);
    u32 byte = (m0.x > 0) | ((m0.y > 0) << 1) | ((m0.z > 0) << 2) | ((m0.w > 0) << 3)
             | ((m1.x > 0) << 4) | ((m1.y > 0) << 5) | ((m1.z > 0) << 6) | ((m1.w > 0) << 7);
    int q  = t >> 8;          // mask row
    int k8 = t & 255;         // byte index within row (keys k8*8..+7)
    // mbt[g8 = k8>>4][q][k8&15]
    mbt[(size_t)(k8 >> 4) * (GG * 16) + (size_t)q * 16 + (k8 & 15)] = (u8)byte;
  }
}

// ---------------------------------------------------------------------------
// Kernel 2: MFMA projection (f16). One wave per (bh, 64-row g-tile):
// [64x128] x [128x48] via 4 m-tiles x 3 n-tiles x 4 k-steps of 16x16x32_f16.
// ---------------------------------------------------------------------------
__global__ __launch_bounds__(64) void proj_mfma(
    const _Float16* __restrict__ hF, const _Float16* __restrict__ Wc,
    _Float16* __restrict__ Qh, _Float16* __restrict__ Kh, _Float16* __restrict__ Vt)
{
  const int bh = blockIdx.x >> 5;
  const int gt = blockIdx.x & 31;
  const int b  = bh >> 3;
  const int hh = bh & (HH - 1);
  const int lane = threadIdx.x;
  const int col  = lane & 15;
  const int quad = lane >> 4;
  const int g0 = gt * 64;

  const _Float16* hb = hF + (size_t)b * GG * DD;
  const _Float16* W  = Wc + (size_t)hh * 48 * DD;

  f32x4 acc[4][3];
  #pragma unroll
  for (int mt = 0; mt < 4; ++mt)
    #pragma unroll
    for (int nt = 0; nt < 3; ++nt)
      acc[mt][nt] = (f32x4){0.f, 0.f, 0.f, 0.f};

  #pragma unroll
  for (int s = 0; s < 4; ++s) {
    h8 a[4], bw[3];
    #pragma unroll
    for (int mt = 0; mt < 4; ++mt)
      a[mt] = *(const h8*)(hb + (size_t)(g0 + mt * 16 + col) * DD + s * 32 + quad * 8);
    #pragma unroll
    for (int nt = 0; nt < 3; ++nt)
      bw[nt] = *(const h8*)(W + (size_t)(nt * 16 + col) * DD + s * 32 + quad * 8);
    #pragma unroll
    for (int mt = 0; mt < 4; ++mt)
      #pragma unroll
      for (int nt = 0; nt < 3; ++nt)
        acc[mt][nt] = __builtin_amdgcn_mfma_f32_16x16x32_f16(a[mt], bw[nt], acc[mt][nt], 0, 0, 0);
  }

  #pragma unroll
  for (int mt = 0; mt < 4; ++mt) {
    #pragma unroll
    for (int r = 0; r < 4; ++r) {
      int g = g0 + mt * 16 + quad * 4 + r;
      Qh[((size_t)bh * GG + g) * 16 + col] = (_Float16)acc[mt][0][r];
      Kh[((size_t)bh * GG + g) * 16 + col] = (_Float16)acc[mt][1][r];
      Vt[((size_t)bh * 16 + col) * GG + g] = (_Float16)acc[mt][2][r];
    }
  }
}

// ---------------------------------------------------------------------------
// Kernel 3: flash attention, zero LDS, XCD-local.
// bh = blockIdx & 31: with round-robin blk%8 XCD dispatch, all q-tiles of a
// bh share one XCD -> K/V (128 KB/bh) stays L2-resident (fixes the measured
// 17.7 MB HBM refetch at 230 GB/s that bounded rounds 2-7).
// 32 q/wave (2 q-tiles share each K/V fragment); per 128-key group: 2
// contiguous 16B mask loads (transposed bitmap) + batched 8 kf + 8 vf loads
// (16 in flight, consumed in issue order -> fine-grained vmcnt).
// ---------------------------------------------------------------------------
__global__ __launch_bounds__(256) void attn_kernel(
    const _Float16* __restrict__ Qh, const _Float16* __restrict__ Kh,
    const _Float16* __restrict__ Vt, const u8* __restrict__ mbt,
    float* __restrict__ out)
{
  const int tid = threadIdx.x, wave = tid >> 6, lane = tid & 63;
  const int col = lane & 15, quad = lane >> 4;
  const int bh = blockIdx.x & 31;          // XCD swizzle: same bh -> same XCD
  const int qb = (blockIdx.x >> 5) * 128 + wave * 32;

  // Q B-frags (16x16x16): B[k=dim][n=q]: n=col, k=quad*4+j -> 8B loads
  const h4 qf0 = *(const h4*)(Qh + ((size_t)bh * GG + qb + col) * 16 + quad * 4);
  const h4 qf1 = *(const h4*)(Qh + ((size_t)bh * GG + qb + 16 + col) * 16 + quad * 4);

  const _Float16* Kb = Kh + (size_t)bh * GG * 16;
  const _Float16* Vb = Vt + ((size_t)bh * 16 + col) * GG;   // row col = vdim
  const u8* mr0 = mbt + (size_t)(qb + col) * 16;            // + g8*(GG*16)
  const u8* mr1 = mbt + (size_t)(qb + 16 + col) * 16;

  f32x4 acc0 = {0.f,0.f,0.f,0.f}, acc1 = {0.f,0.f,0.f,0.f};
  const f32x4 cinit = {-4.f, -4.f, -4.f, -4.f};
  float ls0 = 0.f, ls1 = 0.f;
  const int shq = quad * 4;

  for (int g8 = 0; g8 < 16; ++g8) {       // 16 groups of 128 keys
    const size_t goff = (size_t)g8 * (GG * 16);
    uint4 mv0 = *(const uint4*)(mr0 + goff);   // 128 mask bits, q row 0
    uint4 mv1 = *(const uint4*)(mr1 + goff);   // 128 mask bits, q row 1
    u64 wa0 = (u64)mv0.x | ((u64)mv0.y << 32);
    u64 wa1 = (u64)mv0.z | ((u64)mv0.w << 32);
    u64 wb0 = (u64)mv1.x | ((u64)mv1.y << 32);
    u64 wb1 = (u64)mv1.z | ((u64)mv1.w << 32);

    // batch-issue the group's 16 fragment loads (in-order consumption)
    h4 kf[8], vf[8];
    #pragma unroll
    for (int t = 0; t < 8; ++t) {
      const int kb = g8 * 128 + t * 16;
      kf[t] = *(const h4*)(Kb + (size_t)(kb + col) * 16 + shq);
      vf[t] = *(const h4*)(Vb + kb + shq);
    }

    #pragma unroll
    for (int t = 0; t < 8; ++t) {
      // S^T[key=quad*4+r][q=col], pre-shifted by -4 (cancels in softmax)
      f32x4 s0 = MFMA16(kf[t], qf0, cinit);
      f32x4 s1 = MFMA16(kf[t], qf1, cinit);
      const int sh = (t & 3) * 16 + shq;
      u32 b0 = (u32)(((t < 4) ? wa0 : wa1) >> sh) & 0xFu;
      u32 b1 = (u32)(((t < 4) ? wb0 : wb1) >> sh) & 0xFu;

      float a0 = (b0 & 1u) ? 0.f : EXP2F(s0[0]);
      float a1 = (b0 & 2u) ? 0.f : EXP2F(s0[1]);
      float a2 = (b0 & 4u) ? 0.f : EXP2F(s0[2]);
      float a3 = (b0 & 8u) ? 0.f : EXP2F(s0[3]);
      float c0 = (b1 & 1u) ? 0.f : EXP2F(s1[0]);
      float c1 = (b1 & 2u) ? 0.f : EXP2F(s1[1]);
      float c2 = (b1 & 4u) ? 0.f : EXP2F(s1[2]);
      float c3 = (b1 & 8u) ? 0.f : EXP2F(s1[3]);
      ls0 += (a0 + a1) + (a2 + a3);
      ls1 += (c0 + c1) + (c2 + c3);

      // P pack: exactly the PV B-operand (k=key=quad*4+j, n=q=col)
      h2 pa01 = __builtin_bit_cast(h2, __builtin_amdgcn_cvt_pkrtz(a0, a1));
      h2 pa23 = __builtin_bit_cast(h2, __builtin_amdgcn_cvt_pkrtz(a2, a3));
      h4 pf0 = __builtin_shufflevector(pa01, pa23, 0, 1, 2, 3);
      h2 pc01 = __builtin_bit_cast(h2, __builtin_amdgcn_cvt_pkrtz(c0, c1));
      h2 pc23 = __builtin_bit_cast(h2, __builtin_amdgcn_cvt_pkrtz(c2, c3));
      h4 pf1 = __builtin_shufflevector(pc01, pc23, 0, 1, 2, 3);

      // O^T[vdim][q] += V^T · P  (V-frag shared by both q-tiles)
      acc0 = MFMA16(vf[t], pf0, acc0);
      acc1 = MFMA16(vf[t], pf1, acc1);
    }
  }

  // denominators for q=col (each q-tile): reduce over the 4 quads
  float l0 = ls0; l0 += __shfl_xor(l0, 16, 64); l0 += __shfl_xor(l0, 32, 64);
  float l1 = ls1; l1 += __shfl_xor(l1, 16, 64); l1 += __shfl_xor(l1, 32, 64);
  float r0 = (l0 > 0.f) ? (1.f / l0) : 0.f;   // all-masked row -> 0 (matches ref)
  float r1 = (l1 > 0.f) ? (1.f / l1) : 0.f;

  // O^T C-layout: lane holds vdims quad*4+r of q=col -> float4 stores
  float4 o0 = { acc0[0] * r0, acc0[1] * r0, acc0[2] * r0, acc0[3] * r0 };
  float4 o1 = { acc1[0] * r1, acc1[1] * r1, acc1[2] * r1, acc1[3] * r1 };
  *(float4*)(out + ((size_t)bh * GG + qb + col) * 16 + quad * 4) = o0;
  *(float4*)(out + ((size_t)bh * GG + qb + 16 + col) * 16 + quad * 4) = o1;
}

// ---------------------------------------------------------------------------
extern "C" void kernel_launch(void* const* d_in, const int* in_sizes, int n_in,
                              void* d_out, int out_size, void* d_ws, size_t ws_size,
                              hipStream_t stream) {
  const float* h    = (const float*)d_in[0];
  const int*   mask = (const int*)d_in[1];
  const float* WQ   = (const float*)d_in[2];
  const float* WK   = (const float*)d_in[3];
  const float* WV   = (const float*)d_in[4];
  float* out = (float*)d_out;
  char* ws = (char*)d_ws;     // uses ~8.6 MB
  _Float16* Qh = (_Float16*)(ws + OFF_Q);
  _Float16* Kh = (_Float16*)(ws + OFF_K);
  _Float16* Vt = (_Float16*)(ws + OFF_V);
  u8*       mbt = (u8*)(ws + OFF_M);
  _Float16* hF = (_Float16*)(ws + OFF_H);
  _Float16* Wc = (_Float16*)(ws + OFF_W);

  hipLaunchKernelGGL(prep_kernel, dim3(2752), dim3(256), 0, stream,
                     h, mask, WQ, WK, WV, hF, Wc, mbt);
  hipLaunchKernelGGL(proj_mfma, dim3(BH * (GG / 64)), dim3(64), 0, stream,
                     hF, Wc, Qh, Kh, Vt);
  hipLaunchKernelGGL(attn_kernel, dim3(BH * (GG / 128)), dim3(256), 0, stream,
                     Qh, Kh, Vt, mbt, out);
}